// Round 1
// baseline (365.255 us; speedup 1.0000x reference)
//
#include <hip/hip_runtime.h>
#include <hip/hip_bf16.h>

// QuantizedLinear: y[m][n] = scale * sum_k x[m][k]*(q[n][k]-zp) + bias[n]
// M=8192 (B*S), N=4096 (D_OUT), K=4096 (D_IN).
// Key numerics: (q - zp) is an integer in [-255,255] -> EXACT in bf16.
// Only x->bf16 rounds (rel 2^-9); error << 6.44 threshold.

typedef __attribute__((ext_vector_type(8))) __bf16 bf16x8;
typedef __attribute__((ext_vector_type(4))) float f32x4;
typedef __attribute__((ext_vector_type(4))) int i32x4;
typedef __attribute__((ext_vector_type(8))) unsigned short u16x8;

#define M_DIM 8192
#define N_DIM 4096
#define K_DIM 4096

__device__ __forceinline__ unsigned short f2bf(float f) {
  __hip_bfloat16 h = __float2bfloat16(f);
  unsigned short u;
  __builtin_memcpy(&u, &h, 2);
  return u;
}

// ---- conversion pass 1: x fp32 -> bf16 (8 elems/thread, 16B stores) ----
__global__ __launch_bounds__(256) void cvt_x_kernel(const float* __restrict__ x,
                                                    unsigned short* __restrict__ out) {
  size_t i = (size_t)blockIdx.x * 256 + threadIdx.x;
  f32x4 a = ((const f32x4*)x)[2 * i];
  f32x4 b = ((const f32x4*)x)[2 * i + 1];
  u16x8 o;
  o[0] = f2bf(a[0]); o[1] = f2bf(a[1]); o[2] = f2bf(a[2]); o[3] = f2bf(a[3]);
  o[4] = f2bf(b[0]); o[5] = f2bf(b[1]); o[6] = f2bf(b[2]); o[7] = f2bf(b[3]);
  *(u16x8*)(out + 8 * i) = o;
}

// ---- conversion pass 2: w = (float)q - zp -> bf16 (exact) ----
__global__ __launch_bounds__(256) void cvt_w_kernel(const int* __restrict__ q,
                                                    const float* __restrict__ zp_ptr,
                                                    unsigned short* __restrict__ out) {
  const float zp = *zp_ptr;
  size_t i = (size_t)blockIdx.x * 256 + threadIdx.x;
  i32x4 a = ((const i32x4*)q)[2 * i];
  i32x4 b = ((const i32x4*)q)[2 * i + 1];
  u16x8 o;
  o[0] = f2bf((float)a[0] - zp); o[1] = f2bf((float)a[1] - zp);
  o[2] = f2bf((float)a[2] - zp); o[3] = f2bf((float)a[3] - zp);
  o[4] = f2bf((float)b[0] - zp); o[5] = f2bf((float)b[1] - zp);
  o[6] = f2bf((float)b[2] - zp); o[7] = f2bf((float)b[3] - zp);
  *(u16x8*)(out + 8 * i) = o;
}

// ---- GEMM: 128x128 tile, BK=32, 4 waves (2x2), 16x16x32 bf16 MFMA ----
// MODE 0: A,W pre-converted bf16 in ws; stage via global_load_lds width=16.
// MODE 1: A fp32 / W int32 staged through registers with in-flight conversion
//         (fallback when ws_size is too small for the converted copies).
template <int MODE>
__global__ __launch_bounds__(256, 2) void gemm_kernel(
    const void* __restrict__ Aptr, const void* __restrict__ Wptr,
    const float* __restrict__ scale_ptr, const float* __restrict__ zp_ptr,
    const float* __restrict__ bias, float* __restrict__ C) {
  __shared__ unsigned short As[128 * 32];  // [row][k] linear, 64 B rows
  __shared__ unsigned short Ws[128 * 32];

  const int t = threadIdx.x;
  const int lane = t & 63;
  const int w = t >> 6;
  const int wm = w >> 1;   // wave row (0..1)
  const int wn = w & 1;    // wave col (0..1)

  const size_t gm0 = (size_t)blockIdx.y * 128;
  const size_t gn0 = (size_t)blockIdx.x * 128;

  f32x4 acc[4][4] = {};

  const float zp = (MODE == 1) ? *zp_ptr : 0.0f;

  for (int k0 = 0; k0 < K_DIM; k0 += 32) {
    __syncthreads();  // all waves done reading LDS from previous step
    if constexpr (MODE == 0) {
      const char* Ab = (const char*)Aptr;
      const char* Wb = (const char*)Wptr;
#pragma unroll
      for (int j = 0; j < 2; ++j) {
        const int chunk = w * 2 + j;               // 0..7
        const int row = chunk * 16 + (lane >> 2);  // 0..127
        const int kb = (lane & 3) * 16;            // byte offset in 64B row
        const char* srcA = Ab + ((gm0 + row) * K_DIM + k0) * 2 + kb;
        const char* srcW = Wb + ((gn0 + row) * K_DIM + k0) * 2 + kb;
        __builtin_amdgcn_global_load_lds(
            (const __attribute__((address_space(1))) void*)srcA,
            (__attribute__((address_space(3))) void*)((char*)As + chunk * 1024),
            16, 0, 0);
        __builtin_amdgcn_global_load_lds(
            (const __attribute__((address_space(1))) void*)srcW,
            (__attribute__((address_space(3))) void*)((char*)Ws + chunk * 1024),
            16, 0, 0);
      }
    } else {
      // reg-staged with conversion: thread t handles row t>>1, 16 elems
      const int row = t >> 1;
      const int kh = (t & 1) * 16;
      const float* sa = (const float*)Aptr + (gm0 + row) * (size_t)K_DIM + k0 + kh;
      f32x4 a0 = ((const f32x4*)sa)[0];
      f32x4 a1 = ((const f32x4*)sa)[1];
      f32x4 a2 = ((const f32x4*)sa)[2];
      f32x4 a3 = ((const f32x4*)sa)[3];
      u16x8 o0, o1;
      o0[0] = f2bf(a0[0]); o0[1] = f2bf(a0[1]); o0[2] = f2bf(a0[2]); o0[3] = f2bf(a0[3]);
      o0[4] = f2bf(a1[0]); o0[5] = f2bf(a1[1]); o0[6] = f2bf(a1[2]); o0[7] = f2bf(a1[3]);
      o1[0] = f2bf(a2[0]); o1[1] = f2bf(a2[1]); o1[2] = f2bf(a2[2]); o1[3] = f2bf(a2[3]);
      o1[4] = f2bf(a3[0]); o1[5] = f2bf(a3[1]); o1[6] = f2bf(a3[2]); o1[7] = f2bf(a3[3]);
      *(u16x8*)&As[row * 32 + kh] = o0;
      *(u16x8*)&As[row * 32 + kh + 8] = o1;
      const int* sw = (const int*)Wptr + (gn0 + row) * (size_t)K_DIM + k0 + kh;
      i32x4 w0 = ((const i32x4*)sw)[0];
      i32x4 w1 = ((const i32x4*)sw)[1];
      i32x4 w2 = ((const i32x4*)sw)[2];
      i32x4 w3 = ((const i32x4*)sw)[3];
      u16x8 p0, p1;
      p0[0] = f2bf((float)w0[0] - zp); p0[1] = f2bf((float)w0[1] - zp);
      p0[2] = f2bf((float)w0[2] - zp); p0[3] = f2bf((float)w0[3] - zp);
      p0[4] = f2bf((float)w1[0] - zp); p0[5] = f2bf((float)w1[1] - zp);
      p0[6] = f2bf((float)w1[2] - zp); p0[7] = f2bf((float)w1[3] - zp);
      p1[0] = f2bf((float)w2[0] - zp); p1[1] = f2bf((float)w2[1] - zp);
      p1[2] = f2bf((float)w2[2] - zp); p1[3] = f2bf((float)w2[3] - zp);
      p1[4] = f2bf((float)w3[0] - zp); p1[5] = f2bf((float)w3[1] - zp);
      p1[6] = f2bf((float)w3[2] - zp); p1[7] = f2bf((float)w3[3] - zp);
      *(u16x8*)&Ws[row * 32 + kh] = p0;
      *(u16x8*)&Ws[row * 32 + kh + 8] = p1;
    }
    __syncthreads();  // staging visible (compiler drains vmcnt/lgkmcnt here)

    bf16x8 af[4], bfr[4];
#pragma unroll
    for (int f = 0; f < 4; ++f) {
      const int rowA = wm * 64 + f * 16 + (lane & 15);
      af[f] = *(const bf16x8*)&As[rowA * 32 + (lane >> 4) * 8];
      const int rowB = wn * 64 + f * 16 + (lane & 15);
      bfr[f] = *(const bf16x8*)&Ws[rowB * 32 + (lane >> 4) * 8];
    }
#pragma unroll
    for (int i = 0; i < 4; ++i)
#pragma unroll
      for (int j = 0; j < 4; ++j)
        acc[i][j] = __builtin_amdgcn_mfma_f32_16x16x32_bf16(af[i], bfr[j], acc[i][j], 0, 0, 0);
  }

  const float sc = *scale_ptr;
#pragma unroll
  for (int i = 0; i < 4; ++i) {
    const int rbase = wm * 64 + i * 16 + ((lane >> 4) << 2);
#pragma unroll
    for (int j = 0; j < 4; ++j) {
      const size_t col = gn0 + wn * 64 + j * 16 + (lane & 15);
      const float bv = bias[col];
#pragma unroll
      for (int r = 0; r < 4; ++r) {
        const size_t grow = gm0 + rbase + r;
        C[grow * N_DIM + col] = sc * acc[i][j][r] + bv;
      }
    }
  }
}

extern "C" void kernel_launch(void* const* d_in, const int* in_sizes, int n_in,
                              void* d_out, int out_size, void* d_ws, size_t ws_size,
                              hipStream_t stream) {
  const float* x = (const float*)d_in[0];
  const int* q = (const int*)d_in[1];
  const float* scale = (const float*)d_in[2];
  const float* zp = (const float*)d_in[3];
  const float* bias = (const float*)d_in[4];
  float* out = (float*)d_out;

  const size_t needA = (size_t)M_DIM * K_DIM * 2;  // 64 MiB
  const size_t needW = (size_t)N_DIM * K_DIM * 2;  // 32 MiB
  dim3 grid(N_DIM / 128, M_DIM / 128);

  if (ws_size >= needA + needW) {
    unsigned short* Abf = (unsigned short*)d_ws;
    unsigned short* Wbf = (unsigned short*)((char*)d_ws + needA);
    cvt_x_kernel<<<(M_DIM * (size_t)K_DIM) / (8 * 256), 256, 0, stream>>>(x, Abf);
    cvt_w_kernel<<<(N_DIM * (size_t)K_DIM) / (8 * 256), 256, 0, stream>>>(q, zp, Wbf);
    gemm_kernel<0><<<grid, 256, 0, stream>>>(Abf, Wbf, scale, zp, bias, out);
  } else {
    gemm_kernel<1><<<grid, 256, 0, stream>>>(x, q, scale, zp, bias, out);
  }
}

// Round 2
// 292.732 us; speedup vs baseline: 1.2477x; 1.2477x over previous
//
#include <hip/hip_runtime.h>
#include <hip/hip_bf16.h>

// QuantizedLinear: y[m][n] = scale * sum_k x[m][k]*(q[n][k]-zp) + bias[n]
// M=8192, N=4096, K=4096. (q-zp) integer in [-255,255] -> exact in bf16.
// Structure: cvt passes -> 256^2 8-phase bf16 MFMA GEMM (T1+T2+T3+T4+T5).

typedef __attribute__((ext_vector_type(8))) __bf16 bf16x8;
typedef __attribute__((ext_vector_type(4))) float f32x4;
typedef __attribute__((ext_vector_type(4))) int i32x4;
typedef __attribute__((ext_vector_type(8))) unsigned short u16x8;

#define M_DIM 8192
#define N_DIM 4096
#define K_DIM 4096
#define BM 256
#define BN 256
#define BK 64
#define NT (K_DIM / BK)

#define MFMA16(A, B, C) __builtin_amdgcn_mfma_f32_16x16x32_bf16(A, B, C, 0, 0, 0)

__device__ __forceinline__ unsigned short f2bf(float f) {
  __hip_bfloat16 h = __float2bfloat16(f);
  unsigned short u;
  __builtin_memcpy(&u, &h, 2);
  return u;
}

// ---- conversion pass 1: x fp32 -> bf16 ----
__global__ __launch_bounds__(256) void cvt_x_kernel(const float* __restrict__ x,
                                                    unsigned short* __restrict__ out) {
  size_t i = (size_t)blockIdx.x * 256 + threadIdx.x;
  f32x4 a = ((const f32x4*)x)[2 * i];
  f32x4 b = ((const f32x4*)x)[2 * i + 1];
  u16x8 o;
  o[0] = f2bf(a[0]); o[1] = f2bf(a[1]); o[2] = f2bf(a[2]); o[3] = f2bf(a[3]);
  o[4] = f2bf(b[0]); o[5] = f2bf(b[1]); o[6] = f2bf(b[2]); o[7] = f2bf(b[3]);
  *(u16x8*)(out + 8 * i) = o;
}

// ---- conversion pass 2: w = (float)q - zp -> bf16 (exact) ----
__global__ __launch_bounds__(256) void cvt_w_kernel(const int* __restrict__ q,
                                                    const float* __restrict__ zp_ptr,
                                                    unsigned short* __restrict__ out) {
  const float zp = *zp_ptr;
  size_t i = (size_t)blockIdx.x * 256 + threadIdx.x;
  i32x4 a = ((const i32x4*)q)[2 * i];
  i32x4 b = ((const i32x4*)q)[2 * i + 1];
  u16x8 o;
  o[0] = f2bf((float)a[0] - zp); o[1] = f2bf((float)a[1] - zp);
  o[2] = f2bf((float)a[2] - zp); o[3] = f2bf((float)a[3] - zp);
  o[4] = f2bf((float)b[0] - zp); o[5] = f2bf((float)b[1] - zp);
  o[6] = f2bf((float)b[2] - zp); o[7] = f2bf((float)b[3] - zp);
  *(u16x8*)(out + 8 * i) = o;
}

// Swizzled LDS fragment read: tile is [256 rows][64 bf16], row stride 128B.
// XOR byte bits 4-6 with row bits 0-2 -> ds_read_b128 is bank-uniform (8 words/bank).
__device__ __forceinline__ bf16x8 lds_frag(const char* base, int row, int ks, int lh) {
  int byte = row * 128 + ks * 64 + lh * 16;
  byte ^= ((byte >> 7) & 7) << 4;
  return *(const bf16x8*)(base + byte);
}

// Stage one half-tile (128 rows x 64 bf16 = 16KB): 8 waves x 2 chunks x 1KB.
// LDS dest is linear (wave base + lane*16 by HW); global source is
// inverse-swizzled per-lane so that reads with lds_frag see the right data.
__device__ __forceinline__ void stage_half(const unsigned short* __restrict__ g,
                                           size_t grow0, int k0, char* lds,
                                           int tileOff, int h, int w, int lane) {
#pragma unroll
  for (int j = 0; j < 2; ++j) {
    const int chunk = (w * 2 + j) * 1024;
    const int d = h * 16384 + chunk + lane * 16;        // linear dest byte in tile
    const int sd = d ^ (((d >> 7) & 7) << 4);           // swizzle (involution)
    const int row = sd >> 7;                            // absolute row in tile
    const int colB = sd & 127;                          // byte within row
    const char* src = (const char*)g + ((grow0 + row) * (size_t)K_DIM + k0) * 2 + colB;
    __builtin_amdgcn_global_load_lds(
        (const __attribute__((address_space(1))) void*)src,
        (__attribute__((address_space(3))) void*)(lds + tileOff + h * 16384 + chunk),
        16, 0, 0);
  }
}

// ---- 256x256 8-phase GEMM (2 K-tiles per 8 phases; written as 4 phases/tile) ----
__global__ __launch_bounds__(512, 2) void gemm8_kernel(
    const unsigned short* __restrict__ A, const unsigned short* __restrict__ B,
    const float* __restrict__ scale_ptr, const float* __restrict__ bias,
    float* __restrict__ C) {
  __shared__ __align__(16) char lds[131072];  // buf c: A @ c*65536, B @ c*65536+32768

  const int t = threadIdx.x;
  const int lane = t & 63;
  const int w = t >> 6;      // 0..7
  const int wm = w >> 2;     // 0..1
  const int wn = w & 3;      // 0..3
  const int ll = lane & 15;
  const int lh = lane >> 4;

  // T1: bijective XCD swizzle (nwg = 512, 512 % 8 == 0)
  const int nwg = gridDim.x * gridDim.y;
  const int flat = blockIdx.y * gridDim.x + blockIdx.x;
  const int per = nwg >> 3;
  const int sw = (flat & 7) * per + (flat >> 3);
  const int tn = sw & (N_DIM / BN - 1);
  const int tm = sw / (N_DIM / BN);
  const size_t gm0 = (size_t)tm * BM;
  const size_t gn0 = (size_t)tn * BN;

  f32x4 acc[8][4] = {};  // [mh*4+fi][nh*2+fj]

  // ---- prologue: tile0 (4 halves) + tile1 (B h0,h1 + A h0) = 14 loads/thread ----
  stage_half(A, gm0, 0, lds, 0, 0, w, lane);
  stage_half(A, gm0, 0, lds, 0, 1, w, lane);
  stage_half(B, gn0, 0, lds, 32768, 0, w, lane);
  stage_half(B, gn0, 0, lds, 32768, 1, w, lane);
  stage_half(B, gn0, BK, lds, 65536 + 32768, 0, w, lane);
  stage_half(B, gn0, BK, lds, 65536 + 32768, 1, w, lane);
  stage_half(A, gm0, BK, lds, 65536, 0, w, lane);
  asm volatile("s_waitcnt vmcnt(6)" ::: "memory");  // tile0 complete; 3 halves in flight
  __builtin_amdgcn_s_barrier();

#pragma unroll 2
  for (int T = 0; T < NT; ++T) {
    const int c = T & 1;
    const int aOff = c * 65536;
    const int bOff = c * 65536 + 32768;

    bf16x8 a[4][2], b0[2][2], b1[2][2];

    // ================ phase 1: read A-mh0 + B-nh0; stage A(T+1)h1 ================
#pragma unroll
    for (int fi = 0; fi < 4; ++fi)
#pragma unroll
      for (int ks = 0; ks < 2; ++ks)
        a[fi][ks] = lds_frag(&lds[aOff], wm * 128 + fi * 16 + ll, ks, lh);
#pragma unroll
    for (int fj = 0; fj < 2; ++fj)
#pragma unroll
      for (int ks = 0; ks < 2; ++ks)
        b0[fj][ks] = lds_frag(&lds[bOff], wn * 64 + fj * 16 + ll, ks, lh);
    if (T < NT - 1)
      stage_half(A, gm0, (T + 1) * BK, lds, (c ^ 1) * 65536, 1, w, lane);
    __builtin_amdgcn_s_barrier();
    __builtin_amdgcn_s_setprio(1);
#pragma unroll
    for (int fi = 0; fi < 4; ++fi)
#pragma unroll
      for (int fj = 0; fj < 2; ++fj) {
        acc[fi][fj] = MFMA16(a[fi][0], b0[fj][0], acc[fi][fj]);
        acc[fi][fj] = MFMA16(a[fi][1], b0[fj][1], acc[fi][fj]);
      }
    __builtin_amdgcn_s_setprio(0);
    asm volatile("s_waitcnt lgkmcnt(0)" ::: "memory");
    __builtin_amdgcn_s_barrier();

    // ================ phase 2: read B-nh1 ================
#pragma unroll
    for (int fj = 0; fj < 2; ++fj)
#pragma unroll
      for (int ks = 0; ks < 2; ++ks)
        b1[fj][ks] = lds_frag(&lds[bOff], wn * 64 + 32 + fj * 16 + ll, ks, lh);
    __builtin_amdgcn_s_barrier();
    __builtin_amdgcn_s_setprio(1);
#pragma unroll
    for (int fi = 0; fi < 4; ++fi)
#pragma unroll
      for (int fj = 0; fj < 2; ++fj) {
        acc[fi][2 + fj] = MFMA16(a[fi][0], b1[fj][0], acc[fi][2 + fj]);
        acc[fi][2 + fj] = MFMA16(a[fi][1], b1[fj][1], acc[fi][2 + fj]);
      }
    __builtin_amdgcn_s_setprio(0);
    asm volatile("s_waitcnt lgkmcnt(0)" ::: "memory");
    __builtin_amdgcn_s_barrier();

    // ================ phase 3: read A-mh1; stage B(T+2)h0 ================
#pragma unroll
    for (int fi = 0; fi < 4; ++fi)
#pragma unroll
      for (int ks = 0; ks < 2; ++ks)
        a[fi][ks] = lds_frag(&lds[aOff], wm * 128 + 64 + fi * 16 + ll, ks, lh);
    if (T < NT - 2)
      stage_half(B, gn0, (T + 2) * BK, lds, bOff, 0, w, lane);
    __builtin_amdgcn_s_barrier();
    __builtin_amdgcn_s_setprio(1);
#pragma unroll
    for (int fi = 0; fi < 4; ++fi)
#pragma unroll
      for (int fj = 0; fj < 2; ++fj) {
        acc[4 + fi][2 + fj] = MFMA16(a[fi][0], b1[fj][0], acc[4 + fi][2 + fj]);
        acc[4 + fi][2 + fj] = MFMA16(a[fi][1], b1[fj][1], acc[4 + fi][2 + fj]);
      }
    __builtin_amdgcn_s_setprio(0);
    asm volatile("s_waitcnt lgkmcnt(0)" ::: "memory");
    __builtin_amdgcn_s_barrier();

    // ================ phase 4: stage B(T+2)h1 + A(T+2)h0; counted vmcnt ================
    if (T < NT - 2) {
      stage_half(B, gn0, (T + 2) * BK, lds, bOff, 1, w, lane);
      stage_half(A, gm0, (T + 2) * BK, lds, aOff, 0, w, lane);
    }
    __builtin_amdgcn_s_barrier();
    __builtin_amdgcn_s_setprio(1);
#pragma unroll
    for (int fi = 0; fi < 4; ++fi)
#pragma unroll
      for (int fj = 0; fj < 2; ++fj) {
        acc[4 + fi][fj] = MFMA16(a[fi][0], b0[fj][0], acc[4 + fi][fj]);
        acc[4 + fi][fj] = MFMA16(a[fi][1], b0[fj][1], acc[4 + fi][fj]);
      }
    __builtin_amdgcn_s_setprio(0);
    if (T < NT - 2) {
      asm volatile("s_waitcnt vmcnt(6)" ::: "memory");  // next tile ready; 3 halves in flight
    } else {
      asm volatile("s_waitcnt vmcnt(0)" ::: "memory");  // epilogue drain
    }
    __builtin_amdgcn_s_barrier();
  }

  // ---- epilogue: y = scale*acc + bias ----
  const float sc = *scale_ptr;
#pragma unroll
  for (int nh = 0; nh < 2; ++nh)
#pragma unroll
    for (int fj = 0; fj < 2; ++fj) {
      const size_t col = gn0 + wn * 64 + nh * 32 + fj * 16 + ll;
      const float bv = bias[col];
#pragma unroll
      for (int mh = 0; mh < 2; ++mh)
#pragma unroll
        for (int fi = 0; fi < 4; ++fi) {
          const size_t row0 = gm0 + wm * 128 + mh * 64 + fi * 16 + lh * 4;
          const f32x4 v = acc[mh * 4 + fi][nh * 2 + fj];
#pragma unroll
          for (int r = 0; r < 4; ++r)
            C[(row0 + r) * N_DIM + col] = sc * v[r] + bv;
        }
    }
}

// ---- fallback (small ws): fused-conversion 128^2 GEMM, known-correct from R0 ----
__global__ __launch_bounds__(256, 2) void gemm_fallback_kernel(
    const float* __restrict__ Aptr, const int* __restrict__ Wptr,
    const float* __restrict__ scale_ptr, const float* __restrict__ zp_ptr,
    const float* __restrict__ bias, float* __restrict__ C) {
  __shared__ unsigned short As[128 * 32];
  __shared__ unsigned short Ws[128 * 32];
  const int t = threadIdx.x;
  const int lane = t & 63;
  const int w = t >> 6;
  const int wm = w >> 1, wn = w & 1;
  const size_t gm0 = (size_t)blockIdx.y * 128;
  const size_t gn0 = (size_t)blockIdx.x * 128;
  f32x4 acc[4][4] = {};
  const float zp = *zp_ptr;
  for (int k0 = 0; k0 < K_DIM; k0 += 32) {
    __syncthreads();
    const int row = t >> 1;
    const int kh = (t & 1) * 16;
    const float* sa = Aptr + (gm0 + row) * (size_t)K_DIM + k0 + kh;
    f32x4 a0 = ((const f32x4*)sa)[0], a1 = ((const f32x4*)sa)[1];
    f32x4 a2 = ((const f32x4*)sa)[2], a3 = ((const f32x4*)sa)[3];
    u16x8 o0, o1;
    o0[0] = f2bf(a0[0]); o0[1] = f2bf(a0[1]); o0[2] = f2bf(a0[2]); o0[3] = f2bf(a0[3]);
    o0[4] = f2bf(a1[0]); o0[5] = f2bf(a1[1]); o0[6] = f2bf(a1[2]); o0[7] = f2bf(a1[3]);
    o1[0] = f2bf(a2[0]); o1[1] = f2bf(a2[1]); o1[2] = f2bf(a2[2]); o1[3] = f2bf(a2[3]);
    o1[4] = f2bf(a3[0]); o1[5] = f2bf(a3[1]); o1[6] = f2bf(a3[2]); o1[7] = f2bf(a3[3]);
    *(u16x8*)&As[row * 32 + kh] = o0;
    *(u16x8*)&As[row * 32 + kh + 8] = o1;
    const int* sw = Wptr + (gn0 + row) * (size_t)K_DIM + k0 + kh;
    i32x4 w0 = ((const i32x4*)sw)[0], w1 = ((const i32x4*)sw)[1];
    i32x4 w2 = ((const i32x4*)sw)[2], w3 = ((const i32x4*)sw)[3];
    u16x8 p0, p1;
    p0[0] = f2bf((float)w0[0] - zp); p0[1] = f2bf((float)w0[1] - zp);
    p0[2] = f2bf((float)w0[2] - zp); p0[3] = f2bf((float)w0[3] - zp);
    p0[4] = f2bf((float)w1[0] - zp); p0[5] = f2bf((float)w1[1] - zp);
    p0[6] = f2bf((float)w1[2] - zp); p0[7] = f2bf((float)w1[3] - zp);
    p1[0] = f2bf((float)w2[0] - zp); p1[1] = f2bf((float)w2[1] - zp);
    p1[2] = f2bf((float)w2[2] - zp); p1[3] = f2bf((float)w2[3] - zp);
    p1[4] = f2bf((float)w3[0] - zp); p1[5] = f2bf((float)w3[1] - zp);
    p1[6] = f2bf((float)w3[2] - zp); p1[7] = f2bf((float)w3[3] - zp);
    *(u16x8*)&Ws[row * 32 + kh] = p0;
    *(u16x8*)&Ws[row * 32 + kh + 8] = p1;
    __syncthreads();
    bf16x8 af[4], bfr[4];
#pragma unroll
    for (int f = 0; f < 4; ++f) {
      af[f] = *(const bf16x8*)&As[(wm * 64 + f * 16 + (lane & 15)) * 32 + (lane >> 4) * 8];
      bfr[f] = *(const bf16x8*)&Ws[(wn * 64 + f * 16 + (lane & 15)) * 32 + (lane >> 4) * 8];
    }
#pragma unroll
    for (int i = 0; i < 4; ++i)
#pragma unroll
      for (int j = 0; j < 4; ++j)
        acc[i][j] = MFMA16(af[i], bfr[j], acc[i][j]);
  }
  const float sc = *scale_ptr;
#pragma unroll
  for (int i = 0; i < 4; ++i) {
    const int rbase = wm * 64 + i * 16 + ((lane >> 4) << 2);
#pragma unroll
    for (int j = 0; j < 4; ++j) {
      const size_t col = gn0 + wn * 64 + j * 16 + (lane & 15);
      const float bv = bias[col];
#pragma unroll
      for (int r = 0; r < 4; ++r)
        C[(gm0 + rbase + r) * N_DIM + col] = sc * acc[i][j][r] + bv;
    }
  }
}

extern "C" void kernel_launch(void* const* d_in, const int* in_sizes, int n_in,
                              void* d_out, int out_size, void* d_ws, size_t ws_size,
                              hipStream_t stream) {
  const float* x = (const float*)d_in[0];
  const int* q = (const int*)d_in[1];
  const float* scale = (const float*)d_in[2];
  const float* zp = (const float*)d_in[3];
  const float* bias = (const float*)d_in[4];
  float* out = (float*)d_out;

  const size_t needA = (size_t)M_DIM * K_DIM * 2;  // 64 MiB
  const size_t needW = (size_t)N_DIM * K_DIM * 2;  // 32 MiB

  if (ws_size >= needA + needW) {
    unsigned short* Abf = (unsigned short*)d_ws;
    unsigned short* Wbf = (unsigned short*)((char*)d_ws + needA);
    cvt_x_kernel<<<(M_DIM * (size_t)K_DIM) / (8 * 256), 256, 0, stream>>>(x, Abf);
    cvt_w_kernel<<<(N_DIM * (size_t)K_DIM) / (8 * 256), 256, 0, stream>>>(q, zp, Wbf);
    dim3 grid(N_DIM / BN, M_DIM / BM);  // 16 x 32 = 512
    gemm8_kernel<<<grid, 512, 0, stream>>>(Abf, Wbf, scale, bias, out);
  } else {
    dim3 grid(N_DIM / 128, M_DIM / 128);
    gemm_fallback_kernel<<<grid, 256, 0, stream>>>(x, q, scale, zp, bias, out);
  }
}

// Round 3
// 281.620 us; speedup vs baseline: 1.2970x; 1.0395x over previous
//
#include <hip/hip_runtime.h>
#include <hip/hip_bf16.h>

// QuantizedLinear: y[m][n] = scale * sum_k x[m][k]*(q[n][k]-zp) + bias[n]
// M=8192, N=4096, K=4096. (q-zp) integer in [-255,255] -> exact in bf16.
// cvt passes -> 256^2 single-barrier-per-phase bf16 MFMA GEMM (T1+T2+T3+T4+T5).

typedef __attribute__((ext_vector_type(8))) __bf16 bf16x8;
typedef __attribute__((ext_vector_type(4))) float f32x4;
typedef __attribute__((ext_vector_type(4))) int i32x4;
typedef __attribute__((ext_vector_type(8))) unsigned short u16x8;

#define M_DIM 8192
#define N_DIM 4096
#define K_DIM 4096
#define BM 256
#define BN 256
#define BK 64
#define NT (K_DIM / BK)

#define MFMA16(A, B, C) __builtin_amdgcn_mfma_f32_16x16x32_bf16(A, B, C, 0, 0, 0)

__device__ __forceinline__ unsigned short f2bf(float f) {
  __hip_bfloat16 h = __float2bfloat16(f);
  unsigned short u;
  __builtin_memcpy(&u, &h, 2);
  return u;
}

// ---- conversion pass 1: x fp32 -> bf16 ----
__global__ __launch_bounds__(256) void cvt_x_kernel(const float* __restrict__ x,
                                                    unsigned short* __restrict__ out) {
  size_t i = (size_t)blockIdx.x * 256 + threadIdx.x;
  f32x4 a = ((const f32x4*)x)[2 * i];
  f32x4 b = ((const f32x4*)x)[2 * i + 1];
  u16x8 o;
  o[0] = f2bf(a[0]); o[1] = f2bf(a[1]); o[2] = f2bf(a[2]); o[3] = f2bf(a[3]);
  o[4] = f2bf(b[0]); o[5] = f2bf(b[1]); o[6] = f2bf(b[2]); o[7] = f2bf(b[3]);
  *(u16x8*)(out + 8 * i) = o;
}

// ---- conversion pass 2: w = (float)q - zp -> bf16 (exact) ----
__global__ __launch_bounds__(256) void cvt_w_kernel(const int* __restrict__ q,
                                                    const float* __restrict__ zp_ptr,
                                                    unsigned short* __restrict__ out) {
  const float zp = *zp_ptr;
  size_t i = (size_t)blockIdx.x * 256 + threadIdx.x;
  i32x4 a = ((const i32x4*)q)[2 * i];
  i32x4 b = ((const i32x4*)q)[2 * i + 1];
  u16x8 o;
  o[0] = f2bf((float)a[0] - zp); o[1] = f2bf((float)a[1] - zp);
  o[2] = f2bf((float)a[2] - zp); o[3] = f2bf((float)a[3] - zp);
  o[4] = f2bf((float)b[0] - zp); o[5] = f2bf((float)b[1] - zp);
  o[6] = f2bf((float)b[2] - zp); o[7] = f2bf((float)b[3] - zp);
  *(u16x8*)(out + 8 * i) = o;
}

// Swizzled LDS fragment read: tile is [256 rows][64 bf16], row stride 128B.
// XOR byte bits 4-6 with row bits 0-2 -> ds_read_b128 is bank-uniform.
__device__ __forceinline__ bf16x8 lds_frag(const char* base, int row, int ks, int lh) {
  int byte = row * 128 + ks * 64 + lh * 16;
  byte ^= ((byte >> 7) & 7) << 4;
  return *(const bf16x8*)(base + byte);
}

// Stage one half-tile (128 rows x 64 bf16 = 16KB): 8 waves x 2 chunks x 1KB.
// LDS dest linear (HW: base + lane*16); global source inverse-swizzled.
__device__ __forceinline__ void stage_half(const unsigned short* __restrict__ g,
                                           size_t grow0, int k0, char* lds,
                                           int tileOff, int h, int w, int lane) {
#pragma unroll
  for (int j = 0; j < 2; ++j) {
    const int chunk = (w * 2 + j) * 1024;
    const int d = h * 16384 + chunk + lane * 16;        // linear dest byte in tile
    const int sd = d ^ (((d >> 7) & 7) << 4);           // swizzle (involution)
    const int row = sd >> 7;
    const int colB = sd & 127;
    const char* src = (const char*)g + ((grow0 + row) * (size_t)K_DIM + k0) * 2 + colB;
    __builtin_amdgcn_global_load_lds(
        (const __attribute__((address_space(1))) void*)src,
        (__attribute__((address_space(3))) void*)(lds + tileOff + h * 16384 + chunk),
        16, 0, 0);
  }
}

// Phase tail: counted vmcnt published by the barrier, then wait own ds_reads,
// pin MFMAs after the wait (rule #18), boost priority for the MFMA cluster.
#define PHASE_SYNC(VM)                                         \
  do {                                                         \
    if (T < NT - 2)                                            \
      asm volatile("s_waitcnt vmcnt(" #VM ")" ::: "memory");   \
    else                                                       \
      asm volatile("s_waitcnt vmcnt(0)" ::: "memory");         \
    __builtin_amdgcn_s_barrier();                              \
    asm volatile("s_waitcnt lgkmcnt(0)" ::: "memory");         \
    __builtin_amdgcn_sched_barrier(0);                         \
  } while (0)

#define PHASE_SYNC_NOVM()                                      \
  do {                                                         \
    __builtin_amdgcn_s_barrier();                              \
    asm volatile("s_waitcnt lgkmcnt(0)" ::: "memory");         \
    __builtin_amdgcn_sched_barrier(0);                         \
  } while (0)

// ---- 256x256 GEMM, 4 single-barrier phases per K-tile (BK=64) ----
__global__ __launch_bounds__(512, 2) void gemm8_kernel(
    const unsigned short* __restrict__ A, const unsigned short* __restrict__ B,
    const float* __restrict__ scale_ptr, const float* __restrict__ bias,
    float* __restrict__ C) {
  __shared__ __align__(16) char lds[131072];  // buf c: A @ c*65536, B @ c*65536+32768

  const int t = threadIdx.x;
  const int lane = t & 63;
  const int w = t >> 6;      // 0..7
  const int wm = w >> 2;     // 0..1
  const int wn = w & 3;      // 0..3
  const int ll = lane & 15;
  const int lh = lane >> 4;

  // T1: bijective XCD swizzle (nwg = 512, 512 % 8 == 0)
  const int nwg = gridDim.x * gridDim.y;
  const int flat = blockIdx.y * gridDim.x + blockIdx.x;
  const int per = nwg >> 3;
  const int sw = (flat & 7) * per + (flat >> 3);
  const int tn = sw & (N_DIM / BN - 1);
  const int tm = sw / (N_DIM / BN);
  const size_t gm0 = (size_t)tm * BM;
  const size_t gn0 = (size_t)tn * BN;

  f32x4 acc[8][4] = {};  // [mh*4+fi][nh*2+fj]

  // ---- prologue: tile0 (4 halves) + tile1 (B h0,h1 + A h0) = 14 loads ----
  stage_half(A, gm0, 0, lds, 0, 0, w, lane);
  stage_half(A, gm0, 0, lds, 0, 1, w, lane);
  stage_half(B, gn0, 0, lds, 32768, 0, w, lane);
  stage_half(B, gn0, 0, lds, 32768, 1, w, lane);
  stage_half(B, gn0, BK, lds, 65536 + 32768, 0, w, lane);
  stage_half(B, gn0, BK, lds, 65536 + 32768, 1, w, lane);
  stage_half(A, gm0, BK, lds, 65536, 0, w, lane);
  asm volatile("s_waitcnt vmcnt(6)" ::: "memory");  // tile0 complete; 3 halves in flight
  __builtin_amdgcn_s_barrier();

#pragma unroll 2
  for (int T = 0; T < NT; ++T) {
    const int c = T & 1;
    const int aOff = c * 65536;
    const int bOff = c * 65536 + 32768;

    bf16x8 a[4][2], b0[2][2], b1[2][2];

    // ==== phase 1: read A-mh0 + B-nh0; stage A(T+1)h1; MFMA Q(0,0) ====
#pragma unroll
    for (int fi = 0; fi < 4; ++fi)
#pragma unroll
      for (int ks = 0; ks < 2; ++ks)
        a[fi][ks] = lds_frag(&lds[aOff], wm * 128 + fi * 16 + ll, ks, lh);
#pragma unroll
    for (int fj = 0; fj < 2; ++fj)
#pragma unroll
      for (int ks = 0; ks < 2; ++ks)
        b0[fj][ks] = lds_frag(&lds[bOff], wn * 64 + fj * 16 + ll, ks, lh);
    if (T < NT - 1)
      stage_half(A, gm0, (T + 1) * BK, lds, (c ^ 1) * 65536, 1, w, lane);
    PHASE_SYNC(10);
    __builtin_amdgcn_s_setprio(1);
#pragma unroll
    for (int fi = 0; fi < 4; ++fi)
#pragma unroll
      for (int fj = 0; fj < 2; ++fj) {
        acc[fi][fj] = MFMA16(a[fi][0], b0[fj][0], acc[fi][fj]);
        acc[fi][fj] = MFMA16(a[fi][1], b0[fj][1], acc[fi][fj]);
      }
    __builtin_amdgcn_s_setprio(0);

    // ==== phase 2: read B-nh1; MFMA Q(0,1) ====
#pragma unroll
    for (int fj = 0; fj < 2; ++fj)
#pragma unroll
      for (int ks = 0; ks < 2; ++ks)
        b1[fj][ks] = lds_frag(&lds[bOff], wn * 64 + 32 + fj * 16 + ll, ks, lh);
    PHASE_SYNC(8);
    __builtin_amdgcn_s_setprio(1);
#pragma unroll
    for (int fi = 0; fi < 4; ++fi)
#pragma unroll
      for (int fj = 0; fj < 2; ++fj) {
        acc[fi][2 + fj] = MFMA16(a[fi][0], b1[fj][0], acc[fi][2 + fj]);
        acc[fi][2 + fj] = MFMA16(a[fi][1], b1[fj][1], acc[fi][2 + fj]);
      }
    __builtin_amdgcn_s_setprio(0);

    // ==== phase 3: read A-mh1; stage B(T+2)h0; MFMA Q(1,1) ====
#pragma unroll
    for (int fi = 0; fi < 4; ++fi)
#pragma unroll
      for (int ks = 0; ks < 2; ++ks)
        a[fi][ks] = lds_frag(&lds[aOff], wm * 128 + 64 + fi * 16 + ll, ks, lh);
    if (T < NT - 2)
      stage_half(B, gn0, (T + 2) * BK, lds, bOff, 0, w, lane);
    PHASE_SYNC_NOVM();
    __builtin_amdgcn_s_setprio(1);
#pragma unroll
    for (int fi = 0; fi < 4; ++fi)
#pragma unroll
      for (int fj = 0; fj < 2; ++fj) {
        acc[4 + fi][2 + fj] = MFMA16(a[fi][0], b1[fj][0], acc[4 + fi][2 + fj]);
        acc[4 + fi][2 + fj] = MFMA16(a[fi][1], b1[fj][1], acc[4 + fi][2 + fj]);
      }
    __builtin_amdgcn_s_setprio(0);

    // ==== phase 4: stage B(T+2)h1 + A(T+2)h0; MFMA Q(1,0) ====
    if (T < NT - 2) {
      stage_half(B, gn0, (T + 2) * BK, lds, bOff, 1, w, lane);
      stage_half(A, gm0, (T + 2) * BK, lds, aOff, 0, w, lane);
    }
    PHASE_SYNC(8);
    __builtin_amdgcn_s_setprio(1);
#pragma unroll
    for (int fi = 0; fi < 4; ++fi)
#pragma unroll
      for (int fj = 0; fj < 2; ++fj) {
        acc[4 + fi][fj] = MFMA16(a[fi][0], b0[fj][0], acc[4 + fi][fj]);
        acc[4 + fi][fj] = MFMA16(a[fi][1], b0[fj][1], acc[4 + fi][fj]);
      }
    __builtin_amdgcn_s_setprio(0);
  }

  // ---- epilogue: y = scale*acc + bias ----
  const float sc = *scale_ptr;
#pragma unroll
  for (int nh = 0; nh < 2; ++nh)
#pragma unroll
    for (int fj = 0; fj < 2; ++fj) {
      const size_t col = gn0 + wn * 64 + nh * 32 + fj * 16 + ll;
      const float bv = bias[col];
#pragma unroll
      for (int mh = 0; mh < 2; ++mh)
#pragma unroll
        for (int fi = 0; fi < 4; ++fi) {
          const size_t row0 = gm0 + wm * 128 + mh * 64 + fi * 16 + lh * 4;
          const f32x4 v = acc[mh * 4 + fi][nh * 2 + fj];
#pragma unroll
          for (int r = 0; r < 4; ++r)
            C[(row0 + r) * N_DIM + col] = sc * v[r] + bv;
        }
    }
}

// ---- fallback (small ws): fused-conversion 128^2 GEMM, known-correct from R0 ----
__global__ __launch_bounds__(256, 2) void gemm_fallback_kernel(
    const float* __restrict__ Aptr, const int* __restrict__ Wptr,
    const float* __restrict__ scale_ptr, const float* __restrict__ zp_ptr,
    const float* __restrict__ bias, float* __restrict__ C) {
  __shared__ unsigned short As[128 * 32];
  __shared__ unsigned short Ws[128 * 32];
  const int t = threadIdx.x;
  const int lane = t & 63;
  const int w = t >> 6;
  const int wm = w >> 1, wn = w & 1;
  const size_t gm0 = (size_t)blockIdx.y * 128;
  const size_t gn0 = (size_t)blockIdx.x * 128;
  f32x4 acc[4][4] = {};
  const float zp = *zp_ptr;
  for (int k0 = 0; k0 < K_DIM; k0 += 32) {
    __syncthreads();
    const int row = t >> 1;
    const int kh = (t & 1) * 16;
    const float* sa = Aptr + (gm0 + row) * (size_t)K_DIM + k0 + kh;
    f32x4 a0 = ((const f32x4*)sa)[0], a1 = ((const f32x4*)sa)[1];
    f32x4 a2 = ((const f32x4*)sa)[2], a3 = ((const f32x4*)sa)[3];
    u16x8 o0, o1;
    o0[0] = f2bf(a0[0]); o0[1] = f2bf(a0[1]); o0[2] = f2bf(a0[2]); o0[3] = f2bf(a0[3]);
    o0[4] = f2bf(a1[0]); o0[5] = f2bf(a1[1]); o0[6] = f2bf(a1[2]); o0[7] = f2bf(a1[3]);
    o1[0] = f2bf(a2[0]); o1[1] = f2bf(a2[1]); o1[2] = f2bf(a2[2]); o1[3] = f2bf(a2[3]);
    o1[4] = f2bf(a3[0]); o1[5] = f2bf(a3[1]); o1[6] = f2bf(a3[2]); o1[7] = f2bf(a3[3]);
    *(u16x8*)&As[row * 32 + kh] = o0;
    *(u16x8*)&As[row * 32 + kh + 8] = o1;
    const int* sw = Wptr + (gn0 + row) * (size_t)K_DIM + k0 + kh;
    i32x4 w0 = ((const i32x4*)sw)[0], w1 = ((const i32x4*)sw)[1];
    i32x4 w2 = ((const i32x4*)sw)[2], w3 = ((const i32x4*)sw)[3];
    u16x8 p0, p1;
    p0[0] = f2bf((float)w0[0] - zp); p0[1] = f2bf((float)w0[1] - zp);
    p0[2] = f2bf((float)w0[2] - zp); p0[3] = f2bf((float)w0[3] - zp);
    p0[4] = f2bf((float)w1[0] - zp); p0[5] = f2bf((float)w1[1] - zp);
    p0[6] = f2bf((float)w1[2] - zp); p0[7] = f2bf((float)w1[3] - zp);
    p1[0] = f2bf((float)w2[0] - zp); p1[1] = f2bf((float)w2[1] - zp);
    p1[2] = f2bf((float)w2[2] - zp); p1[3] = f2bf((float)w2[3] - zp);
    p1[4] = f2bf((float)w3[0] - zp); p1[5] = f2bf((float)w3[1] - zp);
    p1[6] = f2bf((float)w3[2] - zp); p1[7] = f2bf((float)w3[3] - zp);
    *(u16x8*)&Ws[row * 32 + kh] = p0;
    *(u16x8*)&Ws[row * 32 + kh + 8] = p1;
    __syncthreads();
    bf16x8 af[4], bfr[4];
#pragma unroll
    for (int f = 0; f < 4; ++f) {
      af[f] = *(const bf16x8*)&As[(wm * 64 + f * 16 + (lane & 15)) * 32 + (lane >> 4) * 8];
      bfr[f] = *(const bf16x8*)&Ws[(wn * 64 + f * 16 + (lane & 15)) * 32 + (lane >> 4) * 8];
    }
#pragma unroll
    for (int i = 0; i < 4; ++i)
#pragma unroll
      for (int j = 0; j < 4; ++j)
        acc[i][j] = MFMA16(af[i], bfr[j], acc[i][j]);
  }
  const float sc = *scale_ptr;
#pragma unroll
  for (int i = 0; i < 4; ++i) {
    const int rbase = wm * 64 + i * 16 + ((lane >> 4) << 2);
#pragma unroll
    for (int j = 0; j < 4; ++j) {
      const size_t col = gn0 + wn * 64 + j * 16 + (lane & 15);
      const float bv = bias[col];
#pragma unroll
      for (int r = 0; r < 4; ++r)
        C[(gm0 + rbase + r) * N_DIM + col] = sc * acc[i][j][r] + bv;
    }
  }
}

extern "C" void kernel_launch(void* const* d_in, const int* in_sizes, int n_in,
                              void* d_out, int out_size, void* d_ws, size_t ws_size,
                              hipStream_t stream) {
  const float* x = (const float*)d_in[0];
  const int* q = (const int*)d_in[1];
  const float* scale = (const float*)d_in[2];
  const float* zp = (const float*)d_in[3];
  const float* bias = (const float*)d_in[4];
  float* out = (float*)d_out;

  const size_t needA = (size_t)M_DIM * K_DIM * 2;  // 64 MiB
  const size_t needW = (size_t)N_DIM * K_DIM * 2;  // 32 MiB

  if (ws_size >= needA + needW) {
    unsigned short* Abf = (unsigned short*)d_ws;
    unsigned short* Wbf = (unsigned short*)((char*)d_ws + needA);
    cvt_x_kernel<<<(M_DIM * (size_t)K_DIM) / (8 * 256), 256, 0, stream>>>(x, Abf);
    cvt_w_kernel<<<(N_DIM * (size_t)K_DIM) / (8 * 256), 256, 0, stream>>>(q, zp, Wbf);
    dim3 grid(N_DIM / BN, M_DIM / BM);  // 16 x 32 = 512
    gemm8_kernel<<<grid, 512, 0, stream>>>(Abf, Wbf, scale, bias, out);
  } else {
    dim3 grid(N_DIM / 128, M_DIM / 128);
    gemm_fallback_kernel<<<grid, 256, 0, stream>>>(x, q, scale, zp, bias, out);
  }
}